// Round 2
// baseline (223.205 us; speedup 1.0000x reference)
//
#include <hip/hip_runtime.h>
#include <cmath>

// SSIM loss, fused separable implementation, round 2.
// X, Y: (16, 4, 512, 512) fp32. 11x11 Gaussian (sigma=1.5), VALID -> 502x502.
// Key change vs round 1: LDS-pipe was the bottleneck (~22/55 ds_read_b32 per
// output in the h/v passes). Now: horizontal pass reads global directly
// (L1-resident) with float4, writes hq via ds_write_b128; vertical pass uses a
// 2x4 register micro-tile with ds_read_b128. ~4.5x less LDS-pipe traffic.

#define WS    11
#define RAD   5
#define OTX   32
#define OTY   32
#define ITY   (OTY + WS - 1)    // 42
#define IMG   512
#define ODIM  (IMG - WS + 1)    // 502
#define TILES 16
#define NC    64
#define NBLOCKS (TILES * TILES * NC)

struct GaussW { float g[WS]; };

__global__ __launch_bounds__(256) void ssim_tile_kernel(
    const float* __restrict__ X, const float* __restrict__ Y,
    float* __restrict__ partial, GaussW gw)
{
    // horizontal pass results: muX, muY, E[XX], E[YY], E[XY]  (26.9 KB)
    __shared__ float hq[5][ITY][OTX];

    const int tid = threadIdx.x;
    const int ox0 = blockIdx.x * OTX;
    const int oy0 = blockIdx.y * OTY;
    const int nc  = blockIdx.z;

    const float* __restrict__ Xp = X + (size_t)nc * IMG * IMG;
    const float* __restrict__ Yp = Y + (size_t)nc * IMG * IMG;

    // ---- Phase A: horizontal 11-tap pass, 1x4 micro-tile per task ----------
    // 42 rows x 8 col-groups = 336 tasks. Reads 16 floats/array from global
    // (4x float4, L1-resident), writes 5x float4 to hq.
    for (int t = tid; t < ITY * 8; t += 256) {
        const int iy  = t >> 3;        // 0..41
        const int gq  = t & 7;         // 0..7 col-group
        const int gy  = oy0 + iy;
        const int gxs = ox0 + gq * 4;

        float xv[16], yv[16];
        if (gy < IMG && gxs + 15 < IMG) {
            const float* xr = Xp + gy * IMG + gxs;
            const float* yr = Yp + gy * IMG + gxs;
#pragma unroll
            for (int j = 0; j < 4; ++j) {
                const float4 a = *(const float4*)(xr + 4 * j);
                const float4 b = *(const float4*)(yr + 4 * j);
                xv[4*j+0] = a.x; xv[4*j+1] = a.y; xv[4*j+2] = a.z; xv[4*j+3] = a.w;
                yv[4*j+0] = b.x; yv[4*j+1] = b.y; yv[4*j+2] = b.z; yv[4*j+3] = b.w;
            }
        } else if (gy < IMG) {
            const float* xr = Xp + gy * IMG;
            const float* yr = Yp + gy * IMG;
#pragma unroll
            for (int j = 0; j < 16; ++j) {
                const int gx = gxs + j;
                const bool ok = gx < IMG;
                xv[j] = ok ? xr[gx] : 0.f;
                yv[j] = ok ? yr[gx] : 0.f;
            }
        } else {
#pragma unroll
            for (int j = 0; j < 16; ++j) { xv[j] = 0.f; yv[j] = 0.f; }
        }

        float aM[4], aN[4], aXX[4], aYY[4], aXY[4];
#pragma unroll
        for (int o = 0; o < 4; ++o) {
            aM[o] = 0.f; aN[o] = 0.f; aXX[o] = 0.f; aYY[o] = 0.f; aXY[o] = 0.f;
        }
#pragma unroll
        for (int j = 0; j < 15; ++j) {
            const float x = xv[j], y = yv[j];
            const float xx = x * x, yy = y * y, xy = x * y;
#pragma unroll
            for (int o = 0; o < 4; ++o) {
                const int k = j - o;                 // compile-time after unroll
                if (k >= 0 && k < WS) {
                    const float w = gw.g[k];
                    aM[o]  = fmaf(w, x,  aM[o]);
                    aN[o]  = fmaf(w, y,  aN[o]);
                    aXX[o] = fmaf(w, xx, aXX[o]);
                    aYY[o] = fmaf(w, yy, aYY[o]);
                    aXY[o] = fmaf(w, xy, aXY[o]);
                }
            }
        }
        *(float4*)&hq[0][iy][gq*4] = make_float4(aM[0],  aM[1],  aM[2],  aM[3]);
        *(float4*)&hq[1][iy][gq*4] = make_float4(aN[0],  aN[1],  aN[2],  aN[3]);
        *(float4*)&hq[2][iy][gq*4] = make_float4(aXX[0], aXX[1], aXX[2], aXX[3]);
        *(float4*)&hq[3][iy][gq*4] = make_float4(aYY[0], aYY[1], aYY[2], aYY[3]);
        *(float4*)&hq[4][iy][gq*4] = make_float4(aXY[0], aXY[1], aXY[2], aXY[3]);
    }
    __syncthreads();

    // ---- Phase B: vertical 11-tap pass, 2x4 micro-tile (128 active thr) ----
    float acc = 0.f;
    if (tid < 128) {
        const int oyl = (tid >> 3) * 2;   // 0,2,..,30
        const int gq  = tid & 7;

        float s[5][8];                    // [quantity][row0 o0..3 | row1 o0..3]
#pragma unroll
        for (int q = 0; q < 5; ++q)
#pragma unroll
            for (int o = 0; o < 8; ++o) s[q][o] = 0.f;

#pragma unroll
        for (int k = 0; k < WS + 1; ++k) {            // 12 hq rows
            const int r = oyl + k;
            float v[5][4];
#pragma unroll
            for (int q = 0; q < 5; ++q) {
                const float4 t4 = *(const float4*)&hq[q][r][gq * 4];
                v[q][0] = t4.x; v[q][1] = t4.y; v[q][2] = t4.z; v[q][3] = t4.w;
            }
            if (k < WS) {
                const float w = gw.g[k];
#pragma unroll
                for (int q = 0; q < 5; ++q)
#pragma unroll
                    for (int o = 0; o < 4; ++o)
                        s[q][o] = fmaf(w, v[q][o], s[q][o]);
            }
            if (k >= 1) {
                const float w = gw.g[k - 1];
#pragma unroll
                for (int q = 0; q < 5; ++q)
#pragma unroll
                    for (int o = 0; o < 4; ++o)
                        s[q][4 + o] = fmaf(w, v[q][o], s[q][4 + o]);
            }
        }

        const float C1 = 1e-4f, C2 = 9e-4f;
#pragma unroll
        for (int row = 0; row < 2; ++row) {
            const int gyv = oy0 + oyl + row;
#pragma unroll
            for (int o = 0; o < 4; ++o) {
                const int gxv = ox0 + gq * 4 + o;
                const float mX  = s[0][row*4+o];
                const float mY  = s[1][row*4+o];
                const float eXX = s[2][row*4+o];
                const float eYY = s[3][row*4+o];
                const float eXY = s[4][row*4+o];
                const float muXX = mX * mX;
                const float muYY = mY * mY;
                const float muXY = mX * mY;
                const float sXX = eXX - muXX;
                const float sYY = eYY - muYY;
                const float sXY = eXY - muXY;
                const float num = (2.f * muXY + C1) * (2.f * sXY + C2);
                const float den = (muXX + muYY + C1) * (sXX + sYY + C2);
                const float val = __fdividef(num, den);
                if (gyv < ODIM && gxv < ODIM) acc += val;
            }
        }
    }

    // ---- deterministic block reduction ----
#pragma unroll
    for (int off = 32; off > 0; off >>= 1)
        acc += __shfl_down(acc, off, 64);

    __shared__ float wsum[4];
    const int wave = tid >> 6, lane = tid & 63;
    if (lane == 0) wsum[wave] = acc;
    __syncthreads();
    if (tid == 0) {
        const float t = (wsum[0] + wsum[1]) + (wsum[2] + wsum[3]);
        partial[((size_t)blockIdx.z * gridDim.y + blockIdx.y) * gridDim.x + blockIdx.x] = t;
    }
}

__global__ __launch_bounds__(256) void ssim_finish_kernel(
    const float* __restrict__ partial, float* __restrict__ out, int n)
{
    __shared__ double sd[256];
    double local = 0.0;
    for (int i = threadIdx.x; i < n; i += 256)
        local += (double)partial[i];
    sd[threadIdx.x] = local;
    __syncthreads();
    for (int s = 128; s > 0; s >>= 1) {
        if (threadIdx.x < s) sd[threadIdx.x] += sd[threadIdx.x + s];
        __syncthreads();
    }
    if (threadIdx.x == 0) {
        const double cnt = (double)NC * (double)ODIM * (double)ODIM;
        out[0] = (float)(1.0 - sd[0] / cnt);
    }
}

extern "C" void kernel_launch(void* const* d_in, const int* in_sizes, int n_in,
                              void* d_out, int out_size, void* d_ws, size_t ws_size,
                              hipStream_t stream) {
    const float* X = (const float*)d_in[0];
    const float* Y = (const float*)d_in[1];
    float* out = (float*)d_out;
    float* partial = (float*)d_ws;   // NBLOCKS floats = 64 KiB

    // Gaussian taps: computed in float64 then rounded to f32 (matches numpy).
    GaussW gw;
    {
        double gd[WS], s = 0.0;
        for (int i = 0; i < WS; ++i) {
            const double x = (double)(i - RAD);
            gd[i] = std::exp(-(x * x) / (2.0 * 1.5 * 1.5));
            s += gd[i];
        }
        for (int i = 0; i < WS; ++i) gw.g[i] = (float)(gd[i] / s);
    }

    dim3 grid(TILES, TILES, NC);
    ssim_tile_kernel<<<grid, 256, 0, stream>>>(X, Y, partial, gw);
    ssim_finish_kernel<<<1, 256, 0, stream>>>(partial, out, NBLOCKS);
}

// Round 3
// 120.223 us; speedup vs baseline: 1.8566x; 1.8566x over previous
//
#include <hip/hip_runtime.h>
#include <hip/hip_bf16.h>
#include <cmath>

// SSIM loss via MFMA, round 3.
// Separable 11-tap Gaussian conv as banded-matrix MFMA (16x16x32 bf16):
//   H: Out[16r x 16c] = X[16 x K=32] * Wh[32 x 16],  Wh[k][j] = w[k-j]
//   V: Out[16r x 16c] = Wv[16 x K=32] * Hq[32 x 16], Wv[r][k] = w[k-r]
// Same per-lane W fragment serves both (A-frag and B-frag index maps match).
// Block: 64x48 output tile, 256 threads, LDS 63.75KB -> 2 blocks/CU.

#define IMG   512
#define ODIM  502            // 512 - 11 + 1
#define BR    64             // output rows per block
#define BC    48             // output cols per block
#define GR    8              // grid rows  (8*64  = 512 >= 502)
#define GC    11             // grid cols  (11*48 = 528 >= 502)
#define NC    64             // batch*channels
#define NBLK  (GR * GC * NC) // 5632

typedef float          f32x4  __attribute__((ext_vector_type(4)));
typedef __bf16         bf16x8 __attribute__((ext_vector_type(8)));
typedef unsigned int   u32x4  __attribute__((ext_vector_type(4)));
typedef unsigned short u16x4  __attribute__((ext_vector_type(4)));

union FU { bf16x8 v; unsigned short u[8]; u32x4 q4; };

__device__ __forceinline__ unsigned short f2b(float f) {   // RNE f32->bf16
    unsigned int b = __builtin_bit_cast(unsigned int, f);
    b = (b + 0x7fffu + ((b >> 16) & 1u)) >> 16;
    return (unsigned short)b;
}
__device__ __forceinline__ float b2f(unsigned short u) {
    return __builtin_bit_cast(float, ((unsigned int)u) << 16);
}

struct GaussW { float g[11]; };

__global__ __launch_bounds__(256) void ssim_mfma_kernel(
    const float* __restrict__ X, const float* __restrict__ Y,
    float* __restrict__ partial, GaussW gw)
{
    __shared__ unsigned short sx[80][72];     // bf16 input tile (rows x cols)
    __shared__ unsigned short sy[80][72];
    __shared__ unsigned short hq[5][48][88];  // H results, TRANSPOSED [q][col][row]

    const int tid = threadIdx.x;
    const int gx0 = blockIdx.x * BC;
    const int gy0 = blockIdx.y * BR;
    const int nc  = blockIdx.z;
    const float* __restrict__ Xp = X + (size_t)nc * IMG * IMG;
    const float* __restrict__ Yp = Y + (size_t)nc * IMG * IMG;

    // ---- stage X,Y -> bf16 LDS (80 rows x 72 cols, zero-padded OOB) ----
    for (int t = tid; t < 80 * 18; t += 256) {
        const int row = t / 18;
        const int cg  = t - row * 18;
        const int gy  = gy0 + row;
        const int gxs = gx0 + cg * 4;
        float xv[4] = {0.f, 0.f, 0.f, 0.f};
        float yv[4] = {0.f, 0.f, 0.f, 0.f};
        if (gy < IMG) {
            if (gxs + 3 < IMG) {
                const float4 a = *(const float4*)(Xp + gy * IMG + gxs);
                const float4 b = *(const float4*)(Yp + gy * IMG + gxs);
                xv[0]=a.x; xv[1]=a.y; xv[2]=a.z; xv[3]=a.w;
                yv[0]=b.x; yv[1]=b.y; yv[2]=b.z; yv[3]=b.w;
            } else {
#pragma unroll
                for (int c = 0; c < 4; ++c) {
                    if (gxs + c < IMG) {
                        xv[c] = Xp[gy * IMG + gxs + c];
                        yv[c] = Yp[gy * IMG + gxs + c];
                    }
                }
            }
        }
        u16x4 px, py;
#pragma unroll
        for (int c = 0; c < 4; ++c) { px[c] = f2b(xv[c]); py[c] = f2b(yv[c]); }
        *(u16x4*)&sx[row][cg * 4] = px;
        *(u16x4*)&sy[row][cg * 4] = py;
    }
    __syncthreads();

    const int lane = tid & 63;
    const int wave = tid >> 6;
    const int m = lane & 15;        // row (A) / col (B) within fragment
    const int g = lane >> 4;        // k-block (8 elems each)

    // ---- banded Gaussian weight fragment (serves as Wh B-frag AND Wv A-frag)
    FU wf;
#pragma unroll
    for (int j = 0; j < 8; ++j) {
        const int d = 8 * g + j - m;
        const float wv =
            (d==0)?gw.g[0]:(d==1)?gw.g[1]:(d==2)?gw.g[2]:(d==3)?gw.g[3]:
            (d==4)?gw.g[4]:(d==5)?gw.g[5]:(d==6)?gw.g[6]:(d==7)?gw.g[7]:
            (d==8)?gw.g[8]:(d==9)?gw.g[9]:(d==10)?gw.g[10]:0.f;
        wf.u[j] = f2b(wv);
    }
    const f32x4 z = {0.f, 0.f, 0.f, 0.f};

    // ---- H stage: 5 row-tiles x 3 col-tiles = 15 MFMA tasks ----
    for (int t = wave; t < 15; t += 4) {
        const int rt = t / 3, ct = t - rt * 3;
        FU fx, fy;
        fx.q4 = *(const u32x4*)&sx[16 * rt + m][16 * ct + 8 * g];
        fy.q4 = *(const u32x4*)&sy[16 * rt + m][16 * ct + 8 * g];
        float xf[8], yf[8];
#pragma unroll
        for (int j = 0; j < 8; ++j) { xf[j] = b2f(fx.u[j]); yf[j] = b2f(fy.u[j]); }
        FU fxx, fyy, fxy;
#pragma unroll
        for (int j = 0; j < 8; ++j) {
            fxx.u[j] = f2b(xf[j] * xf[j]);
            fyy.u[j] = f2b(yf[j] * yf[j]);
            fxy.u[j] = f2b(xf[j] * yf[j]);
        }
        const f32x4 dX  = __builtin_amdgcn_mfma_f32_16x16x32_bf16(fx.v,  wf.v, z, 0, 0, 0);
        const f32x4 dY  = __builtin_amdgcn_mfma_f32_16x16x32_bf16(fy.v,  wf.v, z, 0, 0, 0);
        const f32x4 dXX = __builtin_amdgcn_mfma_f32_16x16x32_bf16(fxx.v, wf.v, z, 0, 0, 0);
        const f32x4 dYY = __builtin_amdgcn_mfma_f32_16x16x32_bf16(fyy.v, wf.v, z, 0, 0, 0);
        const f32x4 dXY = __builtin_amdgcn_mfma_f32_16x16x32_bf16(fxy.v, wf.v, z, 0, 0, 0);
        // D layout: row = 4*g + i, col = m  -> transposed store, 4 rows contiguous
        const int col = 16 * ct + m;
        const int r0  = 16 * rt + 4 * g;
#define STORE_H(Q, D) { u16x4 p; p[0]=f2b(D[0]); p[1]=f2b(D[1]); p[2]=f2b(D[2]); p[3]=f2b(D[3]); \
                        *(u16x4*)&hq[Q][col][r0] = p; }
        STORE_H(0, dX)  STORE_H(1, dY)  STORE_H(2, dXX)  STORE_H(3, dYY)  STORE_H(4, dXY)
#undef STORE_H
    }
    __syncthreads();

    // ---- V stage: 4 row-tiles x 3 col-tiles = 12 MFMA tasks + epilogue ----
    float acc = 0.f;
    for (int t = wave; t < 12; t += 4) {
        const int rt = t / 3, ct = t - rt * 3;
        const int col = 16 * ct + m;       // B-frag col = lane&15
        const int r0  = 16 * rt + 8 * g;   // B-frag k-block
        FU b0, b1, b2, b3, b4;
        b0.q4 = *(const u32x4*)&hq[0][col][r0];
        b1.q4 = *(const u32x4*)&hq[1][col][r0];
        b2.q4 = *(const u32x4*)&hq[2][col][r0];
        b3.q4 = *(const u32x4*)&hq[3][col][r0];
        b4.q4 = *(const u32x4*)&hq[4][col][r0];
        const f32x4 eX  = __builtin_amdgcn_mfma_f32_16x16x32_bf16(wf.v, b0.v, z, 0, 0, 0);
        const f32x4 eY  = __builtin_amdgcn_mfma_f32_16x16x32_bf16(wf.v, b1.v, z, 0, 0, 0);
        const f32x4 eXX = __builtin_amdgcn_mfma_f32_16x16x32_bf16(wf.v, b2.v, z, 0, 0, 0);
        const f32x4 eYY = __builtin_amdgcn_mfma_f32_16x16x32_bf16(wf.v, b3.v, z, 0, 0, 0);
        const f32x4 eXY = __builtin_amdgcn_mfma_f32_16x16x32_bf16(wf.v, b4.v, z, 0, 0, 0);
        const float C1 = 1e-4f, C2 = 9e-4f;
#pragma unroll
        for (int i = 0; i < 4; ++i) {
            const int gy = gy0 + 16 * rt + 4 * g + i;
            const int gx = gx0 + col;
            const float mX = eX[i], mY = eY[i];
            const float muXX = mX * mX;
            const float muYY = mY * mY;
            const float muXY = mX * mY;
            const float sXX = eXX[i] - muXX;
            const float sYY = eYY[i] - muYY;
            const float sXY = eXY[i] - muXY;
            const float num = (2.f * muXY + C1) * (2.f * sXY + C2);
            const float den = (muXX + muYY + C1) * (sXX + sYY + C2);
            const float val = __fdividef(num, den);
            if (gy < ODIM && gx < ODIM) acc += val;
        }
    }

    // ---- deterministic block reduction ----
#pragma unroll
    for (int off = 32; off > 0; off >>= 1)
        acc += __shfl_down(acc, off, 64);

    __shared__ float wsum[4];
    if (lane == 0) wsum[wave] = acc;
    __syncthreads();
    if (tid == 0) {
        const float tsum = (wsum[0] + wsum[1]) + (wsum[2] + wsum[3]);
        partial[((size_t)blockIdx.z * gridDim.y + blockIdx.y) * gridDim.x + blockIdx.x] = tsum;
    }
}

__global__ __launch_bounds__(256) void ssim_finish_kernel(
    const float* __restrict__ partial, float* __restrict__ out, int n)
{
    __shared__ double sd[256];
    double local = 0.0;
    for (int i = threadIdx.x; i < n; i += 256)
        local += (double)partial[i];
    sd[threadIdx.x] = local;
    __syncthreads();
    for (int s = 128; s > 0; s >>= 1) {
        if (threadIdx.x < s) sd[threadIdx.x] += sd[threadIdx.x + s];
        __syncthreads();
    }
    if (threadIdx.x == 0) {
        const double cnt = (double)NC * (double)ODIM * (double)ODIM;
        out[0] = (float)(1.0 - sd[0] / cnt);
    }
}

extern "C" void kernel_launch(void* const* d_in, const int* in_sizes, int n_in,
                              void* d_out, int out_size, void* d_ws, size_t ws_size,
                              hipStream_t stream) {
    const float* X = (const float*)d_in[0];
    const float* Y = (const float*)d_in[1];
    float* out = (float*)d_out;
    float* partial = (float*)d_ws;   // NBLK floats = 22.5 KiB

    // Gaussian taps in float64 -> f32 (matches numpy reference construction).
    GaussW gw;
    {
        double gd[11], s = 0.0;
        for (int i = 0; i < 11; ++i) {
            const double x = (double)(i - 5);
            gd[i] = std::exp(-(x * x) / (2.0 * 1.5 * 1.5));
            s += gd[i];
        }
        for (int i = 0; i < 11; ++i) gw.g[i] = (float)(gd[i] / s);
    }

    dim3 grid(GC, GR, NC);
    ssim_mfma_kernel<<<grid, 256, 0, stream>>>(X, Y, partial, gw);
    ssim_finish_kernel<<<1, 256, 0, stream>>>(partial, out, NBLK);
}

// Round 4
// 65.509 us; speedup vs baseline: 3.4072x; 1.8352x over previous
//
#include <hip/hip_runtime.h>
#include <hip/hip_bf16.h>
#include <cmath>

// SSIM loss via MFMA, round 4.
// Separable 11-tap Gaussian conv as banded-matrix MFMA (16x16x32 bf16).
// vs round 3: no raw-tile LDS staging (H reads global direct, L1/L2-resident),
// hardware bf16 converts (v_cvt_pk via scalar casts), weight frag from a tiny
// LDS band LUT, 64x32 tile -> 29.3KB LDS -> 5 blocks/CU.

#define IMG   512
#define ODIM  502            // 512 - 11 + 1
#define BR    64             // output rows per block
#define BC    32             // output cols per block
#define GR    8              // 8*64  = 512
#define GC    16             // 16*32 = 512
#define NC    64             // batch*channels
#define NBLK  (GR * GC * NC) // 8192
#define HROWS 88             // hq padded row stride (44 words -> free 2-way banks)

typedef float          f32x4  __attribute__((ext_vector_type(4)));
typedef __bf16         bf16x8 __attribute__((ext_vector_type(8)));
typedef unsigned int   u32x4  __attribute__((ext_vector_type(4)));
typedef unsigned short u16x4  __attribute__((ext_vector_type(4)));

union FU { bf16x8 v; __bf16 b[8]; unsigned short u[8]; u32x4 q4; };

__device__ __forceinline__ unsigned short bfbits(float f) {
    __bf16 h = (__bf16)f;                     // hardware cvt (RNE)
    return __builtin_bit_cast(unsigned short, h);
}

struct GaussW { float g[11]; };

__global__ __launch_bounds__(256) void ssim_mfma_kernel(
    const float* __restrict__ X, const float* __restrict__ Y,
    float* __restrict__ partial, GaussW gw)
{
    __shared__ unsigned short hq[5][BC][HROWS]; // H results, [q][col][row], 28.2KB
    __shared__ unsigned short wl[16][36];       // band weights, wl[m][k] = w[k-m]

    const int tid = threadIdx.x;
    const int gx0 = blockIdx.x * BC;
    const int gy0 = blockIdx.y * BR;
    const int nc  = blockIdx.z;
    const float* __restrict__ Xp = X + (size_t)nc * IMG * IMG;
    const float* __restrict__ Yp = Y + (size_t)nc * IMG * IMG;

    // ---- fill weight band LUT (one value per thread x2) ----
    for (int t = tid; t < 16 * 32; t += 256) {
        const int mm = t >> 5, kk = t & 31;
        const int d = kk - mm;
        wl[mm][kk] = bfbits((d >= 0 && d < 11) ? gw.g[d] : 0.f);
    }
    __syncthreads();

    const int lane = tid & 63;
    const int wave = tid >> 6;
    const int m = lane & 15;        // A row / B col within fragment
    const int g = lane >> 4;        // k-block (8 elems)

    FU wf;                          // serves as H B-frag AND V A-frag
    wf.q4 = *(const u32x4*)&wl[m][8 * g];
    const f32x4 z = {0.f, 0.f, 0.f, 0.f};

    // ---- H stage: 5 row-tiles x 2 col-tiles = 10 MFMA tasks ----
    for (int t = wave; t < 10; t += 4) {
        const int rt = t >> 1, ct = t & 1;
        const int gy = min(gy0 + 16 * rt + m, IMG - 1);       // clamp: garbage
        const int cs = min(gx0 + 16 * ct + 8 * g, IMG - 8);   // flows only to
        const float* xr = Xp + gy * IMG + cs;                 // masked outputs
        const float* yr = Yp + gy * IMG + cs;
        const f32x4 a0 = *(const f32x4*)xr;
        const f32x4 a1 = *(const f32x4*)(xr + 4);
        const f32x4 b0 = *(const f32x4*)yr;
        const f32x4 b1 = *(const f32x4*)(yr + 4);
        float xf[8], yf[8];
#pragma unroll
        for (int j = 0; j < 4; ++j) {
            xf[j] = a0[j]; xf[4 + j] = a1[j];
            yf[j] = b0[j]; yf[4 + j] = b1[j];
        }
        FU fx, fy, fxx, fyy, fxy;
#pragma unroll
        for (int j = 0; j < 8; ++j) {
            fx.b[j]  = (__bf16)xf[j];
            fy.b[j]  = (__bf16)yf[j];
            fxx.b[j] = (__bf16)(xf[j] * xf[j]);
            fyy.b[j] = (__bf16)(yf[j] * yf[j]);
            fxy.b[j] = (__bf16)(xf[j] * yf[j]);
        }
        const f32x4 dX  = __builtin_amdgcn_mfma_f32_16x16x32_bf16(fx.v,  wf.v, z, 0, 0, 0);
        const f32x4 dY  = __builtin_amdgcn_mfma_f32_16x16x32_bf16(fy.v,  wf.v, z, 0, 0, 0);
        const f32x4 dXX = __builtin_amdgcn_mfma_f32_16x16x32_bf16(fxx.v, wf.v, z, 0, 0, 0);
        const f32x4 dYY = __builtin_amdgcn_mfma_f32_16x16x32_bf16(fyy.v, wf.v, z, 0, 0, 0);
        const f32x4 dXY = __builtin_amdgcn_mfma_f32_16x16x32_bf16(fxy.v, wf.v, z, 0, 0, 0);
        // D layout: row = 4g+i, col = m  -> transposed store, 4 rows contiguous
        const int col = 16 * ct + m;
        const int r0  = 16 * rt + 4 * g;
#define STORE_H(Q, D) { u16x4 p; p[0]=bfbits(D[0]); p[1]=bfbits(D[1]); \
                        p[2]=bfbits(D[2]); p[3]=bfbits(D[3]); \
                        *(u16x4*)&hq[Q][col][r0] = p; }
        STORE_H(0, dX)  STORE_H(1, dY)  STORE_H(2, dXX)  STORE_H(3, dYY)  STORE_H(4, dXY)
#undef STORE_H
    }
    __syncthreads();

    // ---- V stage: 4 row-tiles x 2 col-tiles = 8 MFMA tasks + epilogue ----
    float acc = 0.f;
    for (int t = wave; t < 8; t += 4) {
        const int rt = t >> 1, ct = t & 1;
        const int col = 16 * ct + m;       // B-frag col
        const int r0  = 16 * rt + 8 * g;   // B-frag k-block
        FU b0, b1, b2, b3, b4;
        b0.q4 = *(const u32x4*)&hq[0][col][r0];
        b1.q4 = *(const u32x4*)&hq[1][col][r0];
        b2.q4 = *(const u32x4*)&hq[2][col][r0];
        b3.q4 = *(const u32x4*)&hq[3][col][r0];
        b4.q4 = *(const u32x4*)&hq[4][col][r0];
        const f32x4 eX  = __builtin_amdgcn_mfma_f32_16x16x32_bf16(wf.v, b0.v, z, 0, 0, 0);
        const f32x4 eY  = __builtin_amdgcn_mfma_f32_16x16x32_bf16(wf.v, b1.v, z, 0, 0, 0);
        const f32x4 eXX = __builtin_amdgcn_mfma_f32_16x16x32_bf16(wf.v, b2.v, z, 0, 0, 0);
        const f32x4 eYY = __builtin_amdgcn_mfma_f32_16x16x32_bf16(wf.v, b3.v, z, 0, 0, 0);
        const f32x4 eXY = __builtin_amdgcn_mfma_f32_16x16x32_bf16(wf.v, b4.v, z, 0, 0, 0);
        const float C1 = 1e-4f, C2 = 9e-4f;
#pragma unroll
        for (int i = 0; i < 4; ++i) {
            const int gy = gy0 + 16 * rt + 4 * g + i;
            const int gx = gx0 + col;
            const float mX = eX[i], mY = eY[i];
            const float muXX = mX * mX;
            const float muYY = mY * mY;
            const float muXY = mX * mY;
            const float sXX = eXX[i] - muXX;
            const float sYY = eYY[i] - muYY;
            const float sXY = eXY[i] - muXY;
            const float num = (2.f * muXY + C1) * (2.f * sXY + C2);
            const float den = (muXX + muYY + C1) * (sXX + sYY + C2);
            const float val = __fdividef(num, den);
            if (gy < ODIM && gx < ODIM) acc += val;
        }
    }

    // ---- deterministic block reduction ----
#pragma unroll
    for (int off = 32; off > 0; off >>= 1)
        acc += __shfl_down(acc, off, 64);

    __shared__ float wsum[4];
    if (lane == 0) wsum[wave] = acc;
    __syncthreads();
    if (tid == 0) {
        const float tsum = (wsum[0] + wsum[1]) + (wsum[2] + wsum[3]);
        partial[((size_t)blockIdx.z * gridDim.y + blockIdx.y) * gridDim.x + blockIdx.x] = tsum;
    }
}

__global__ __launch_bounds__(256) void ssim_finish_kernel(
    const float* __restrict__ partial, float* __restrict__ out, int n)
{
    __shared__ double sd[256];
    double local = 0.0;
    for (int i = threadIdx.x; i < n; i += 256)
        local += (double)partial[i];
    sd[threadIdx.x] = local;
    __syncthreads();
    for (int s = 128; s > 0; s >>= 1) {
        if (threadIdx.x < s) sd[threadIdx.x] += sd[threadIdx.x + s];
        __syncthreads();
    }
    if (threadIdx.x == 0) {
        const double cnt = (double)NC * (double)ODIM * (double)ODIM;
        out[0] = (float)(1.0 - sd[0] / cnt);
    }
}

extern "C" void kernel_launch(void* const* d_in, const int* in_sizes, int n_in,
                              void* d_out, int out_size, void* d_ws, size_t ws_size,
                              hipStream_t stream) {
    const float* X = (const float*)d_in[0];
    const float* Y = (const float*)d_in[1];
    float* out = (float*)d_out;
    float* partial = (float*)d_ws;   // NBLK floats = 32 KiB

    // Gaussian taps in float64 -> f32 (matches numpy reference construction).
    GaussW gw;
    {
        double gd[11], s = 0.0;
        for (int i = 0; i < 11; ++i) {
            const double x = (double)(i - 5);
            gd[i] = std::exp(-(x * x) / (2.0 * 1.5 * 1.5));
            s += gd[i];
        }
        for (int i = 0; i < 11; ++i) gw.g[i] = (float)(gd[i] / s);
    }

    dim3 grid(GC, GR, NC);
    ssim_mfma_kernel<<<grid, 256, 0, stream>>>(X, Y, partial, gw);
    ssim_finish_kernel<<<1, 256, 0, stream>>>(partial, out, NBLK);
}

// Round 5
// 56.637 us; speedup vs baseline: 3.9410x; 1.1566x over previous
//
#include <hip/hip_runtime.h>
#include <hip/hip_bf16.h>
#include <cmath>

// SSIM loss via MFMA, round 5.
// Separable 11-tap Gaussian conv as banded-matrix MFMA (16x16x32 bf16).
// vs round 4: __launch_bounds__(256,5) (VGPR cap ~102, ILP unlocked), fully
// unrolled H/V task loops with static indices, hq stride 90 (odd word stride
// -> conflict-free LDS writes AND reads), vectorized 512-thread finish.

#define IMG   512
#define ODIM  502            // 512 - 11 + 1
#define BR    64             // output rows per block
#define BC    32             // output cols per block
#define GR    8              // 8*64  = 512
#define GC    16             // 16*32 = 512
#define NC    64             // batch*channels
#define NBLK  (GR * GC * NC) // 8192
#define HROWS 90             // hq padded row stride (45 words, odd -> no conflicts)

typedef float          f32x4  __attribute__((ext_vector_type(4)));
typedef __bf16         bf16x8 __attribute__((ext_vector_type(8)));
typedef unsigned int   u32x4  __attribute__((ext_vector_type(4)));
typedef unsigned short u16x4  __attribute__((ext_vector_type(4)));

union FU { bf16x8 v; __bf16 b[8]; unsigned short u[8]; u32x4 q4; };

__device__ __forceinline__ unsigned short bfbits(float f) {
    __bf16 h = (__bf16)f;                     // hardware cvt (RNE)
    return __builtin_bit_cast(unsigned short, h);
}

struct GaussW { float g[11]; };

__global__ __launch_bounds__(256, 5) void ssim_mfma_kernel(
    const float* __restrict__ X, const float* __restrict__ Y,
    float* __restrict__ partial, GaussW gw)
{
    __shared__ unsigned short hq[5][BC][HROWS]; // H results, [q][col][row], 28.8KB
    __shared__ unsigned short wl[16][36];       // band weights, wl[m][k] = w[k-m]

    const int tid = threadIdx.x;
    const int gx0 = blockIdx.x * BC;
    const int gy0 = blockIdx.y * BR;
    const int nc  = blockIdx.z;
    const float* __restrict__ Xp = X + (size_t)nc * IMG * IMG;
    const float* __restrict__ Yp = Y + (size_t)nc * IMG * IMG;

    // ---- fill weight band LUT ----
#pragma unroll
    for (int it = 0; it < 2; ++it) {
        const int t = tid + 256 * it;
        const int mm = t >> 5, kk = t & 31;
        const int d = kk - mm;
        wl[mm][kk] = bfbits((d >= 0 && d < 11) ? gw.g[d] : 0.f);
    }
    __syncthreads();

    const int lane = tid & 63;
    const int wave = tid >> 6;
    const int m = lane & 15;        // A row / B col within fragment
    const int g = lane >> 4;        // k-block (8 elems)

    FU wf;                          // serves as H B-frag AND V A-frag
    wf.q4 = *(const u32x4*)&wl[m][8 * g];
    const f32x4 z = {0.f, 0.f, 0.f, 0.f};

    // ---- H stage: 10 MFMA tasks, fully unrolled (3 iters, uniform guard) ----
#pragma unroll
    for (int it = 0; it < 3; ++it) {
        const int t = wave + 4 * it;
        if (t < 10) {
            const int rt = t >> 1, ct = t & 1;
            const int gy = min(gy0 + 16 * rt + m, IMG - 1);       // clamp: garbage
            const int cs = min(gx0 + 16 * ct + 8 * g, IMG - 8);   // flows only to
            const float* xr = Xp + gy * IMG + cs;                 // masked outputs
            const float* yr = Yp + gy * IMG + cs;
            const f32x4 a0 = *(const f32x4*)xr;
            const f32x4 a1 = *(const f32x4*)(xr + 4);
            const f32x4 b0 = *(const f32x4*)yr;
            const f32x4 b1 = *(const f32x4*)(yr + 4);
            float xf[8], yf[8];
#pragma unroll
            for (int j = 0; j < 4; ++j) {
                xf[j] = a0[j]; xf[4 + j] = a1[j];
                yf[j] = b0[j]; yf[4 + j] = b1[j];
            }
            FU fx, fy, fxx, fyy, fxy;
#pragma unroll
            for (int j = 0; j < 8; ++j) {
                fx.b[j]  = (__bf16)xf[j];
                fy.b[j]  = (__bf16)yf[j];
                fxx.b[j] = (__bf16)(xf[j] * xf[j]);
                fyy.b[j] = (__bf16)(yf[j] * yf[j]);
                fxy.b[j] = (__bf16)(xf[j] * yf[j]);
            }
            const f32x4 dX  = __builtin_amdgcn_mfma_f32_16x16x32_bf16(fx.v,  wf.v, z, 0, 0, 0);
            const f32x4 dY  = __builtin_amdgcn_mfma_f32_16x16x32_bf16(fy.v,  wf.v, z, 0, 0, 0);
            const f32x4 dXX = __builtin_amdgcn_mfma_f32_16x16x32_bf16(fxx.v, wf.v, z, 0, 0, 0);
            const f32x4 dYY = __builtin_amdgcn_mfma_f32_16x16x32_bf16(fyy.v, wf.v, z, 0, 0, 0);
            const f32x4 dXY = __builtin_amdgcn_mfma_f32_16x16x32_bf16(fxy.v, wf.v, z, 0, 0, 0);
            // D layout: row = 4g+i, col = m  -> transposed store, 4 rows contiguous
            const int col = 16 * ct + m;
            const int r0  = 16 * rt + 4 * g;
#define STORE_H(Q, D) { u16x4 p; p[0]=bfbits(D[0]); p[1]=bfbits(D[1]); \
                        p[2]=bfbits(D[2]); p[3]=bfbits(D[3]); \
                        *(u16x4*)&hq[Q][col][r0] = p; }
            STORE_H(0, dX)  STORE_H(1, dY)  STORE_H(2, dXX)  STORE_H(3, dYY)  STORE_H(4, dXY)
#undef STORE_H
        }
    }
    __syncthreads();

    // ---- V stage: 8 MFMA tasks, fully unrolled (2 iters) + epilogue ----
    float acc = 0.f;
#pragma unroll
    for (int it = 0; it < 2; ++it) {
        const int t = wave + 4 * it;
        const int rt = t >> 1, ct = t & 1;
        const int col = 16 * ct + m;       // B-frag col
        const int r0  = 16 * rt + 8 * g;   // B-frag k-block
        FU b0, b1, b2, b3, b4;
        b0.q4 = *(const u32x4*)&hq[0][col][r0];
        b1.q4 = *(const u32x4*)&hq[1][col][r0];
        b2.q4 = *(const u32x4*)&hq[2][col][r0];
        b3.q4 = *(const u32x4*)&hq[3][col][r0];
        b4.q4 = *(const u32x4*)&hq[4][col][r0];
        const f32x4 eX  = __builtin_amdgcn_mfma_f32_16x16x32_bf16(wf.v, b0.v, z, 0, 0, 0);
        const f32x4 eY  = __builtin_amdgcn_mfma_f32_16x16x32_bf16(wf.v, b1.v, z, 0, 0, 0);
        const f32x4 eXX = __builtin_amdgcn_mfma_f32_16x16x32_bf16(wf.v, b2.v, z, 0, 0, 0);
        const f32x4 eYY = __builtin_amdgcn_mfma_f32_16x16x32_bf16(wf.v, b3.v, z, 0, 0, 0);
        const f32x4 eXY = __builtin_amdgcn_mfma_f32_16x16x32_bf16(wf.v, b4.v, z, 0, 0, 0);
        const float C1 = 1e-4f, C2 = 9e-4f;
#pragma unroll
        for (int i = 0; i < 4; ++i) {
            const int gy = gy0 + 16 * rt + 4 * g + i;
            const int gx = gx0 + col;
            const float mX = eX[i], mY = eY[i];
            const float muXX = mX * mX;
            const float muYY = mY * mY;
            const float muXY = mX * mY;
            const float sXX = eXX[i] - muXX;
            const float sYY = eYY[i] - muYY;
            const float sXY = eXY[i] - muXY;
            const float num = (2.f * muXY + C1) * (2.f * sXY + C2);
            const float den = (muXX + muYY + C1) * (sXX + sYY + C2);
            const float val = __fdividef(num, den);
            if (gy < ODIM && gx < ODIM) acc += val;
        }
    }

    // ---- deterministic block reduction ----
#pragma unroll
    for (int off = 32; off > 0; off >>= 1)
        acc += __shfl_down(acc, off, 64);

    __shared__ float wsum[4];
    if (lane == 0) wsum[wave] = acc;
    __syncthreads();
    if (tid == 0) {
        const float tsum = (wsum[0] + wsum[1]) + (wsum[2] + wsum[3]);
        partial[((size_t)blockIdx.z * gridDim.y + blockIdx.y) * gridDim.x + blockIdx.x] = tsum;
    }
}

__global__ __launch_bounds__(512) void ssim_finish_kernel(
    const float* __restrict__ partial, float* __restrict__ out)
{
    __shared__ double sd[512];
    const float4* p4 = (const float4*)partial;   // NBLK = 8192 = 512*4*4
    double local = 0.0;
#pragma unroll
    for (int i = 0; i < 4; ++i) {
        const float4 v = p4[threadIdx.x + 512 * i];
        local += ((double)v.x + (double)v.y) + ((double)v.z + (double)v.w);
    }
    sd[threadIdx.x] = local;
    __syncthreads();
    for (int s = 256; s > 0; s >>= 1) {
        if (threadIdx.x < s) sd[threadIdx.x] += sd[threadIdx.x + s];
        __syncthreads();
    }
    if (threadIdx.x == 0) {
        const double cnt = (double)NC * (double)ODIM * (double)ODIM;
        out[0] = (float)(1.0 - sd[0] / cnt);
    }
}

extern "C" void kernel_launch(void* const* d_in, const int* in_sizes, int n_in,
                              void* d_out, int out_size, void* d_ws, size_t ws_size,
                              hipStream_t stream) {
    const float* X = (const float*)d_in[0];
    const float* Y = (const float*)d_in[1];
    float* out = (float*)d_out;
    float* partial = (float*)d_ws;   // NBLK floats = 32 KiB

    // Gaussian taps in float64 -> f32 (matches numpy reference construction).
    GaussW gw;
    {
        double gd[11], s = 0.0;
        for (int i = 0; i < 11; ++i) {
            const double x = (double)(i - 5);
            gd[i] = std::exp(-(x * x) / (2.0 * 1.5 * 1.5));
            s += gd[i];
        }
        for (int i = 0; i < 11; ++i) gw.g[i] = (float)(gd[i] / s);
    }

    dim3 grid(GC, GR, NC);
    ssim_mfma_kernel<<<grid, 256, 0, stream>>>(X, Y, partial, gw);
    ssim_finish_kernel<<<1, 512, 0, stream>>>(partial, out);
}

// Round 7
// 50.926 us; speedup vs baseline: 4.3829x; 1.1121x over previous
//
#include <hip/hip_runtime.h>
#include <hip/hip_bf16.h>
#include <cmath>

// SSIM loss via MFMA, round 7: strip-per-wave, all-register pipeline.
// H pass: 16x16x32 bf16 MFMA (A=data rows, B=banded Gaussian W).
// Key trick: H's D-layout (lane: rows 4g+i, col m) IS the B-frag layout of a
// K=16 MFMA (lane: k=4g+j, col m). So V pass = 2 chained mfma_16x16x16_bf16
// per quantity, B-frags taken DIRECTLY from H result registers. No hq LDS,
// no mid-kernel barrier, waves independent. Each wave owns a 16col x 64row
// output strip; block = 4 adjacent strips (64x64 out tile).
// vs round 6: direct call to __builtin_amdgcn_mfma_f32_16x16x16bf16_1k
// (no __has_builtin guard -- it returns false on the HOST pass and broke
// the build; aux-target builtins parse fine in both passes).

#define IMG   512
#define ODIM  502            // 512 - 11 + 1
#define SC    16             // strip cols (per wave)
#define BR    64             // strip rows
#define WPB   4              // waves per block
#define BC    (SC * WPB)     // 64 block cols
#define GX    8              // 512/64
#define GY    8              // 512/64
#define NC    64             // batch*channels
#define NBLK  (GX * GY * NC) // 4096

typedef float          f32x4  __attribute__((ext_vector_type(4)));
typedef __bf16         bf16x8 __attribute__((ext_vector_type(8)));
typedef __bf16         bf16x4 __attribute__((ext_vector_type(4)));
typedef short          s16x4  __attribute__((ext_vector_type(4)));
typedef unsigned int   u32x2  __attribute__((ext_vector_type(2)));
typedef unsigned int   u32x4  __attribute__((ext_vector_type(4)));

union F8 { bf16x8 v; __bf16 b[8]; u32x4 q; };
union F4 { bf16x4 v; s16x4 s; __bf16 b[4]; u32x2 q; };

__device__ __forceinline__ unsigned short bfbits(float f) {
    __bf16 h = (__bf16)f;
    return __builtin_bit_cast(unsigned short, h);
}

__device__ __forceinline__ f32x4 mfma16(const F4& a, const F4& b, f32x4 c) {
    return __builtin_amdgcn_mfma_f32_16x16x16bf16_1k(a.s, b.s, c, 0, 0, 0);
}

struct GaussW { float g[11]; };

__global__ __launch_bounds__(256, 4) void ssim_mfma_kernel(
    const float* __restrict__ X, const float* __restrict__ Y,
    float* __restrict__ partial, GaussW gw)
{
    __shared__ unsigned short wl[16][32];   // band weights: wl[m][k] = w[k-m]
    __shared__ float wsum[WPB];

    const int tid  = threadIdx.x;
    const int lane = tid & 63;
    const int wave = tid >> 6;
    const int m    = lane & 15;
    const int g    = lane >> 4;

    // ---- weight band LUT (1 KB, filled once) ----
#pragma unroll
    for (int it = 0; it < 2; ++it) {
        const int t  = tid + 256 * it;
        const int mm = t >> 5, kk = t & 31;
        const int d  = kk - mm;
        wl[mm][kk] = bfbits((d >= 0 && d < 11) ? gw.g[d] : 0.f);
    }
    __syncthreads();

    const int gx0 = blockIdx.x * BC + SC * wave;   // this wave's strip
    const int gy0 = blockIdx.y * BR;
    const int nc  = blockIdx.z;
    const float* __restrict__ Xp = X + (size_t)nc * IMG * IMG;
    const float* __restrict__ Yp = Y + (size_t)nc * IMG * IMG;

    F8 wf;  wf.q  = *(const u32x4*)&wl[m][8 * g];       // H B-frag: w[8g+j - m]
    F4 wa0; wa0.q = *(const u32x2*)&wl[m][4 * g];       // V A chunk0: w[4g+j - m]
    F4 wa1; wa1.q = *(const u32x2*)&wl[m][16 + 4 * g];  // V A chunk1: w[16+4g+j - m]
    const f32x4 z = {0.f, 0.f, 0.f, 0.f};

    // ---- H stage: 5 input row-tiles, results kept in registers ----
    // h[rt][q]: lane (m,g) holds Hq[gy0+16rt+4g+i][gx0+m] as bf16x4
    F4 h[5][5];
    const int cs = min(gx0 + 8 * g, IMG - 8);   // clamped: garbage cols get
                                                // zero weight for valid outputs
#pragma unroll
    for (int rt = 0; rt < 5; ++rt) {
        const int gy = min(gy0 + 16 * rt + m, IMG - 1);
        const float* xr = Xp + gy * IMG + cs;
        const float* yr = Yp + gy * IMG + cs;
        const f32x4 a0 = *(const f32x4*)xr;
        const f32x4 a1 = *(const f32x4*)(xr + 4);
        const f32x4 b0 = *(const f32x4*)yr;
        const f32x4 b1 = *(const f32x4*)(yr + 4);

        F8 fx, fy, fxx, fyy, fxy;
#pragma unroll
        for (int j = 0; j < 4; ++j) {
            fx.b[j]      = (__bf16)a0[j];
            fx.b[4 + j]  = (__bf16)a1[j];
            fy.b[j]      = (__bf16)b0[j];
            fy.b[4 + j]  = (__bf16)b1[j];
            fxx.b[j]     = (__bf16)(a0[j] * a0[j]);
            fxx.b[4 + j] = (__bf16)(a1[j] * a1[j]);
            fyy.b[j]     = (__bf16)(b0[j] * b0[j]);
            fyy.b[4 + j] = (__bf16)(b1[j] * b1[j]);
            fxy.b[j]     = (__bf16)(a0[j] * b0[j]);
            fxy.b[4 + j] = (__bf16)(a1[j] * b1[j]);
        }
        const f32x4 dX  = __builtin_amdgcn_mfma_f32_16x16x32_bf16(fx.v,  wf.v, z, 0, 0, 0);
        const f32x4 dY  = __builtin_amdgcn_mfma_f32_16x16x32_bf16(fy.v,  wf.v, z, 0, 0, 0);
        const f32x4 dXX = __builtin_amdgcn_mfma_f32_16x16x32_bf16(fxx.v, wf.v, z, 0, 0, 0);
        const f32x4 dYY = __builtin_amdgcn_mfma_f32_16x16x32_bf16(fyy.v, wf.v, z, 0, 0, 0);
        const f32x4 dXY = __builtin_amdgcn_mfma_f32_16x16x32_bf16(fxy.v, wf.v, z, 0, 0, 0);
#pragma unroll
        for (int i = 0; i < 4; ++i) {
            h[rt][0].b[i] = (__bf16)dX[i];
            h[rt][1].b[i] = (__bf16)dY[i];
            h[rt][2].b[i] = (__bf16)dXX[i];
            h[rt][3].b[i] = (__bf16)dYY[i];
            h[rt][4].b[i] = (__bf16)dXY[i];
        }
    }

    // ---- V stage: 4 output row-tiles, B-frags straight from h[] ----
    float acc = 0.f;
#pragma unroll
    for (int vt = 0; vt < 4; ++vt) {
        f32x4 e[5];
#pragma unroll
        for (int q = 0; q < 5; ++q) {
            e[q] = mfma16(wa1, h[vt + 1][q], z);
            e[q] = mfma16(wa0, h[vt][q], e[q]);
        }
        const float C1 = 1e-4f, C2 = 9e-4f;
#pragma unroll
        for (int i = 0; i < 4; ++i) {
            const int gy = gy0 + 16 * vt + 4 * g + i;
            const int gx = gx0 + m;
            const float mX = e[0][i], mY = e[1][i];
            const float muXX = mX * mX;
            const float muYY = mY * mY;
            const float muXY = mX * mY;
            const float sXX = e[2][i] - muXX;
            const float sYY = e[3][i] - muYY;
            const float sXY = e[4][i] - muXY;
            const float num = (2.f * muXY + C1) * (2.f * sXY + C2);
            const float den = (muXX + muYY + C1) * (sXX + sYY + C2);
            const float val = __fdividef(num, den);
            if (gy < ODIM && gx < ODIM) acc += val;
        }
    }

    // ---- deterministic block reduction ----
#pragma unroll
    for (int off = 32; off > 0; off >>= 1)
        acc += __shfl_down(acc, off, 64);

    if (lane == 0) wsum[wave] = acc;
    __syncthreads();
    if (tid == 0) {
        const float tsum = (wsum[0] + wsum[1]) + (wsum[2] + wsum[3]);
        partial[((size_t)blockIdx.z * gridDim.y + blockIdx.y) * gridDim.x + blockIdx.x] = tsum;
    }
}

__global__ __launch_bounds__(512) void ssim_finish_kernel(
    const float* __restrict__ partial, float* __restrict__ out)
{
    __shared__ double sd[512];
    const float4* p4 = (const float4*)partial;   // NBLK = 4096 = 512*2*4
    double local = 0.0;
#pragma unroll
    for (int i = 0; i < 2; ++i) {
        const float4 v = p4[threadIdx.x + 512 * i];
        local += ((double)v.x + (double)v.y) + ((double)v.z + (double)v.w);
    }
    sd[threadIdx.x] = local;
    __syncthreads();
    for (int s = 256; s > 0; s >>= 1) {
        if (threadIdx.x < s) sd[threadIdx.x] += sd[threadIdx.x + s];
        __syncthreads();
    }
    if (threadIdx.x == 0) {
        const double cnt = (double)NC * (double)ODIM * (double)ODIM;
        out[0] = (float)(1.0 - sd[0] / cnt);
    }
}

extern "C" void kernel_launch(void* const* d_in, const int* in_sizes, int n_in,
                              void* d_out, int out_size, void* d_ws, size_t ws_size,
                              hipStream_t stream) {
    const float* X = (const float*)d_in[0];
    const float* Y = (const float*)d_in[1];
    float* out = (float*)d_out;
    float* partial = (float*)d_ws;   // NBLK floats = 16 KiB

    // Gaussian taps in float64 -> f32 (matches numpy reference construction).
    GaussW gw;
    {
        double gd[11], s = 0.0;
        for (int i = 0; i < 11; ++i) {
            const double x = (double)(i - 5);
            gd[i] = std::exp(-(x * x) / (2.0 * 1.5 * 1.5));
            s += gd[i];
        }
        for (int i = 0; i < 11; ++i) gw.g[i] = (float)(gd[i] / s);
    }

    dim3 grid(GX, GY, NC);
    ssim_mfma_kernel<<<grid, 256, 0, stream>>>(X, Y, partial, gw);
    ssim_finish_kernel<<<1, 512, 0, stream>>>(partial, out);
}

// Round 8
// 48.159 us; speedup vs baseline: 4.6348x; 1.0575x over previous
//
#include <hip/hip_runtime.h>
#include <hip/hip_bf16.h>
#include <cmath>

// SSIM loss via MFMA, round 8: tall strips + live-2 H-tile register pipeline.
// H pass: 16x16x32 bf16 MFMA (A=data rows, B=banded Gaussian W).
// H's D-layout (lane: rows 4g+i, col m) IS the B-frag layout of a K=16 MFMA
// (lane: k=4g+j, col m), so V = 2 chained mfma_16x16x16_bf16 per quantity with
// B-frags straight from H result registers. No hq LDS, no mid-kernel barrier.
// vs round 7: strip = 16 cols x 128 rows (9 H tiles, 8 V tiles), only TWO
// H tiles live at a time (parity-indexed, fully unrolled -> static indices),
// __launch_bounds__(256,5) for 5 waves/SIMD. Weight LUT stride 40 shorts
// (80 B) keeps the b128 fragment read 16B-aligned and <=2-way banked.

#define IMG   512
#define ODIM  502            // 512 - 11 + 1
#define SC    16             // strip cols (per wave)
#define BR    128            // strip rows
#define WPB   4              // waves per block
#define BC    (SC * WPB)     // 64 block cols
#define GX    8              // 512/64
#define GY    4              // 512/128
#define NC    64             // batch*channels
#define NBLK  (GX * GY * NC) // 2048
#define NVT   8              // V tiles per strip (8*16 = 128 rows)

typedef float          f32x4  __attribute__((ext_vector_type(4)));
typedef __bf16         bf16x8 __attribute__((ext_vector_type(8)));
typedef __bf16         bf16x4 __attribute__((ext_vector_type(4)));
typedef short          s16x4  __attribute__((ext_vector_type(4)));
typedef unsigned int   u32x2  __attribute__((ext_vector_type(2)));
typedef unsigned int   u32x4  __attribute__((ext_vector_type(4)));

union F8 { bf16x8 v; __bf16 b[8]; u32x4 q; };
union F4 { bf16x4 v; s16x4 s; __bf16 b[4]; u32x2 q; };

__device__ __forceinline__ unsigned short bfbits(float f) {
    __bf16 h = (__bf16)f;
    return __builtin_bit_cast(unsigned short, h);
}

__device__ __forceinline__ f32x4 mfma16(const F4& a, const F4& b, f32x4 c) {
    return __builtin_amdgcn_mfma_f32_16x16x16bf16_1k(a.s, b.s, c, 0, 0, 0);
}

struct GaussW { float g[11]; };

__global__ __launch_bounds__(256, 5) void ssim_mfma_kernel(
    const float* __restrict__ X, const float* __restrict__ Y,
    float* __restrict__ partial, GaussW gw)
{
    __shared__ unsigned short wl[16][40];   // band weights: wl[m][k] = w[k-m]
    __shared__ float wsum[WPB];

    const int tid  = threadIdx.x;
    const int lane = tid & 63;
    const int wave = tid >> 6;
    const int m    = lane & 15;
    const int g    = lane >> 4;

    // ---- weight band LUT (1.25 KB, filled once) ----
    for (int t = tid; t < 16 * 40; t += 256) {
        const int mm = t / 40, kk = t - 40 * mm;
        const int d  = kk - mm;
        wl[mm][kk] = bfbits((kk < 32 && d >= 0 && d < 11) ? gw.g[d] : 0.f);
    }
    __syncthreads();

    const int gx0 = blockIdx.x * BC + SC * wave;   // this wave's strip
    const int gy0 = blockIdx.y * BR;
    const int nc  = blockIdx.z;
    const float* __restrict__ Xp = X + (size_t)nc * IMG * IMG;
    const float* __restrict__ Yp = Y + (size_t)nc * IMG * IMG;

    F8 wf;  wf.q  = *(const u32x4*)&wl[m][8 * g];       // H B-frag: w[8g+j - m]
    F4 wa0; wa0.q = *(const u32x2*)&wl[m][4 * g];       // V A chunk0: w[4g+j - m]
    F4 wa1; wa1.q = *(const u32x2*)&wl[m][16 + 4 * g];  // V A chunk1: w[16+4g+j - m]
    const f32x4 z = {0.f, 0.f, 0.f, 0.f};

    const int cs = min(gx0 + 8 * g, IMG - 8);   // clamped cols feed only masked
                                                // outputs (band is zero there)

    // H-tile producer: hd[q] <- lane (m,g) holds Hq[gy0+16rt+4g+i][gx0+m]
    auto computeH = [&](F4 (&hd)[5], int rt) {
        const int gy = min(gy0 + 16 * rt + m, IMG - 1);
        const float* xr = Xp + gy * IMG + cs;
        const float* yr = Yp + gy * IMG + cs;
        const f32x4 a0 = *(const f32x4*)xr;
        const f32x4 a1 = *(const f32x4*)(xr + 4);
        const f32x4 b0 = *(const f32x4*)yr;
        const f32x4 b1 = *(const f32x4*)(yr + 4);

        F8 fx, fy, fxx, fyy, fxy;
#pragma unroll
        for (int j = 0; j < 4; ++j) {
            fx.b[j]      = (__bf16)a0[j];
            fx.b[4 + j]  = (__bf16)a1[j];
            fy.b[j]      = (__bf16)b0[j];
            fy.b[4 + j]  = (__bf16)b1[j];
            fxx.b[j]     = (__bf16)(a0[j] * a0[j]);
            fxx.b[4 + j] = (__bf16)(a1[j] * a1[j]);
            fyy.b[j]     = (__bf16)(b0[j] * b0[j]);
            fyy.b[4 + j] = (__bf16)(b1[j] * b1[j]);
            fxy.b[j]     = (__bf16)(a0[j] * b0[j]);
            fxy.b[4 + j] = (__bf16)(a1[j] * b1[j]);
        }
        const f32x4 dX  = __builtin_amdgcn_mfma_f32_16x16x32_bf16(fx.v,  wf.v, z, 0, 0, 0);
        const f32x4 dY  = __builtin_amdgcn_mfma_f32_16x16x32_bf16(fy.v,  wf.v, z, 0, 0, 0);
        const f32x4 dXX = __builtin_amdgcn_mfma_f32_16x16x32_bf16(fxx.v, wf.v, z, 0, 0, 0);
        const f32x4 dYY = __builtin_amdgcn_mfma_f32_16x16x32_bf16(fyy.v, wf.v, z, 0, 0, 0);
        const f32x4 dXY = __builtin_amdgcn_mfma_f32_16x16x32_bf16(fxy.v, wf.v, z, 0, 0, 0);
#pragma unroll
        for (int i = 0; i < 4; ++i) {
            hd[0].b[i] = (__bf16)dX[i];
            hd[1].b[i] = (__bf16)dY[i];
            hd[2].b[i] = (__bf16)dXX[i];
            hd[3].b[i] = (__bf16)dYY[i];
            hd[4].b[i] = (__bf16)dXY[i];
        }
    };

    F4 hh[2][5];                 // live-2 H tiles (parity-indexed, static
    computeH(hh[0], 0);          // after full unroll)

    float acc = 0.f;
#pragma unroll
    for (int vt = 0; vt < NVT; ++vt) {
        computeH(hh[(vt + 1) & 1], vt + 1);
        const F4 (&h0)[5] = hh[vt & 1];
        const F4 (&h1)[5] = hh[(vt + 1) & 1];

        f32x4 e[5];
#pragma unroll
        for (int q = 0; q < 5; ++q) {
            e[q] = mfma16(wa1, h1[q], z);
            e[q] = mfma16(wa0, h0[q], e[q]);
        }
        const float C1 = 1e-4f, C2 = 9e-4f;
#pragma unroll
        for (int i = 0; i < 4; ++i) {
            const int gy = gy0 + 16 * vt + 4 * g + i;
            const int gx = gx0 + m;
            const float mX = e[0][i], mY = e[1][i];
            const float muXX = mX * mX;
            const float muYY = mY * mY;
            const float muXY = mX * mY;
            const float sXX = e[2][i] - muXX;
            const float sYY = e[3][i] - muYY;
            const float sXY = e[4][i] - muXY;
            const float num = (2.f * muXY + C1) * (2.f * sXY + C2);
            const float den = (muXX + muYY + C1) * (sXX + sYY + C2);
            const float val = __fdividef(num, den);
            if (gy < ODIM && gx < ODIM) acc += val;
        }
    }

    // ---- deterministic block reduction ----
#pragma unroll
    for (int off = 32; off > 0; off >>= 1)
        acc += __shfl_down(acc, off, 64);

    if (lane == 0) wsum[wave] = acc;
    __syncthreads();
    if (tid == 0) {
        const float tsum = (wsum[0] + wsum[1]) + (wsum[2] + wsum[3]);
        partial[((size_t)blockIdx.z * gridDim.y + blockIdx.y) * gridDim.x + blockIdx.x] = tsum;
    }
}

__global__ __launch_bounds__(512) void ssim_finish_kernel(
    const float* __restrict__ partial, float* __restrict__ out)
{
    __shared__ double sd[512];
    const float4* p4 = (const float4*)partial;   // NBLK = 2048 = 512*4
    const float4 v = p4[threadIdx.x];
    double local = ((double)v.x + (double)v.y) + ((double)v.z + (double)v.w);
    sd[threadIdx.x] = local;
    __syncthreads();
    for (int s = 256; s > 0; s >>= 1) {
        if (threadIdx.x < s) sd[threadIdx.x] += sd[threadIdx.x + s];
        __syncthreads();
    }
    if (threadIdx.x == 0) {
        const double cnt = (double)NC * (double)ODIM * (double)ODIM;
        out[0] = (float)(1.0 - sd[0] / cnt);
    }
}

extern "C" void kernel_launch(void* const* d_in, const int* in_sizes, int n_in,
                              void* d_out, int out_size, void* d_ws, size_t ws_size,
                              hipStream_t stream) {
    const float* X = (const float*)d_in[0];
    const float* Y = (const float*)d_in[1];
    float* out = (float*)d_out;
    float* partial = (float*)d_ws;   // NBLK floats = 8 KiB

    // Gaussian taps in float64 -> f32 (matches numpy reference construction).
    GaussW gw;
    {
        double gd[11], s = 0.0;
        for (int i = 0; i < 11; ++i) {
            const double x = (double)(i - 5);
            gd[i] = std::exp(-(x * x) / (2.0 * 1.5 * 1.5));
            s += gd[i];
        }
        for (int i = 0; i < 11; ++i) gw.g[i] = (float)(gd[i] / s);
    }

    dim3 grid(GX, GY, NC);
    ssim_mfma_kernel<<<grid, 256, 0, stream>>>(X, Y, partial, gw);
    ssim_finish_kernel<<<1, 512, 0, stream>>>(partial, out);
}